// Round 2
// baseline (354.303 us; speedup 1.0000x reference)
//
#include <hip/hip_runtime.h>
#include <hip/hip_bf16.h>

// VectorQuantiser: x [32,64,64,64] f32, embeddings [64,1024] f32.
// N=131072 rows of D=64; argmin_k ||z - e_k||^2 over K=1024; output = gathered
// codewords (STE forward value), f32 [N,64].
//
//   k0 vq_prep:   transpose E -> ET[k][d]; ckseq[k] = f32 sequential sum_d e^2
//                 (emulates numpy axis-0 reduce order)
//   k1 vq_main:   tiled f32 distance GEMM + per-row top-2 + fused gather;
//                 rows with (2nd - best) < MARGIN go to refine list
//   k2 vq_refine: for listed rows, emulate the NUMPY f32 reference chain
//                 (pairwise-8 ||z||^2, sequential-FMA sim, f32 dist at ~64
//                 magnitude -> ULP ~7.6e-6 tie quantization, first-index
//                 argmin) and rewrite those output rows.

#define NROWS (32 * 64 * 64)   // 131072
#define DIM   64
#define KCB   1024
#define KC    128
#define RB    64
#define MARGIN 1e-4f

// ws layout (bytes):
#define ET_OFF    0           // float[1024*64] = 262144
#define CK_OFF    262144      // float[1024]    = 4096
#define CNT_OFF   266240      // int (+pad)
#define LIST_OFF  266496      // int[cap]

__global__ void vq_prep(const float* __restrict__ E,
                        float* __restrict__ ET,
                        float* __restrict__ ckseq) {
    #pragma clang fp contract(off)
    int k = blockIdx.x * blockDim.x + threadIdx.x;  // 0..1023
    if (k >= KCB) return;
    float c = 0.f;
    #pragma unroll 8
    for (int d = 0; d < DIM; ++d) {
        float v = E[d * KCB + k];          // coalesced along k
        ET[k * DIM + d] = v;
        float q = v * v;                   // rounded square (numpy elementwise)
        c = c + q;                         // sequential d=0..63 (numpy axis-0)
    }
    ckseq[k] = c;
}

__global__ __launch_bounds__(256)
void vq_main(const float* __restrict__ x, const float* __restrict__ E,
             const float* __restrict__ ckf, const float* __restrict__ ET,
             float* __restrict__ out, int* __restrict__ count,
             int* __restrict__ list, int list_cap) {
    __shared__ float xs[RB * 68];        // x tile [r][d], stride 68
    __shared__ float es[DIM * KC];       // E chunk [d][k]
    __shared__ float ckc[KC];
    __shared__ int   rowidx[RB];

    const int tid = threadIdx.x;
    const int rowbase = blockIdx.x * RB;
    const int tx = tid & 15, ty = tid >> 4;

    // stage x tile (coalesced float4)
    const float4* x4 = (const float4*)(x + rowbase * DIM);
    #pragma unroll
    for (int p = 0; p < 4; ++p) {
        int f = p * 256 + tid;           // 0..1023
        int r = f >> 4, dq = f & 15;
        float4 v = x4[f];
        *(float4*)&xs[r * 68 + dq * 4] = v;
    }

    float b1[4], b2[4];
    int   id1[4];
    #pragma unroll
    for (int i = 0; i < 4; ++i) { b1[i] = 1e30f; b2[i] = 1e30f; id1[i] = 0; }

    const float4* E4 = (const float4*)E;
    for (int c = 0; c < KCB / KC; ++c) {
        __syncthreads();   // protect es/xs from previous phase readers
        #pragma unroll
        for (int p = 0; p < 8; ++p) {
            int f = p * 256 + tid;       // 0..2047
            int d = f >> 5, k4 = f & 31;
            float4 v = E4[d * 256 + c * 32 + k4];
            *(float4*)&es[d * KC + k4 * 4] = v;
        }
        if (tid < KC / 4)
            ((float4*)ckc)[tid] = ((const float4*)(ckf + c * KC))[tid];
        __syncthreads();

        float acc[4][8];
        #pragma unroll
        for (int i = 0; i < 4; ++i)
            #pragma unroll
            for (int j = 0; j < 8; ++j) acc[i][j] = 0.f;

        #pragma unroll 2
        for (int dq = 0; dq < 16; ++dq) {
            float4 xv[4];
            #pragma unroll
            for (int i = 0; i < 4; ++i)
                xv[i] = *(const float4*)&xs[(ty + 16 * i) * 68 + dq * 4];
            #pragma unroll
            for (int j = 0; j < 8; ++j) {
                int k = tx + 16 * j;
                float e0 = es[(dq * 4 + 0) * KC + k];
                float e1 = es[(dq * 4 + 1) * KC + k];
                float e2 = es[(dq * 4 + 2) * KC + k];
                float e3 = es[(dq * 4 + 3) * KC + k];
                #pragma unroll
                for (int i = 0; i < 4; ++i) {
                    acc[i][j] = fmaf(xv[i].x, e0, acc[i][j]);
                    acc[i][j] = fmaf(xv[i].y, e1, acc[i][j]);
                    acc[i][j] = fmaf(xv[i].z, e2, acc[i][j]);
                    acc[i][j] = fmaf(xv[i].w, e3, acc[i][j]);
                }
            }
        }

        #pragma unroll
        for (int j = 0; j < 8; ++j) {
            int k = tx + 16 * j;
            float cv = ckc[k];
            int gk = c * KC + k;
            #pragma unroll
            for (int i = 0; i < 4; ++i) {
                float s = fmaf(-2.f, acc[i][j], cv);
                if (s < b1[i]) { b2[i] = b1[i]; b1[i] = s; id1[i] = gk; }
                else if (s < b2[i]) { b2[i] = s; }
            }
        }
    }

    // block-level per-row top-2 merge (stride 17 to avoid bank conflicts)
    __syncthreads();
    float* rb1 = es;                 // 64*17 = 1088 floats
    float* rb2 = es + 1088;
    int*   rid = (int*)(es + 2176);
    #pragma unroll
    for (int i = 0; i < 4; ++i) {
        int r = ty + 16 * i;
        rb1[r * 17 + tx] = b1[i];
        rb2[r * 17 + tx] = b2[i];
        rid[r * 17 + tx] = id1[i];
    }
    __syncthreads();
    if (tid < RB) {
        int r = tid;
        float fb1 = 1e30f, fb2 = 1e30f;
        int fid = 0;
        for (int t = 0; t < 16; ++t) {
            float v1 = rb1[r * 17 + t];
            float v2 = rb2[r * 17 + t];
            int   vi = rid[r * 17 + t];
            if (v1 < fb1 || (v1 == fb1 && vi < fid)) { fb2 = fb1; fb1 = v1; fid = vi; }
            else if (v1 < fb2) fb2 = v1;
            if (v2 < fb2) fb2 = v2;
        }
        rowidx[r] = fid;
        if (fb2 - fb1 < MARGIN) {
            int slot = atomicAdd(count, 1);
            if (slot < list_cap) list[slot] = rowbase + r;
        }
    }
    __syncthreads();

    // fused gather: out[rowbase+r][:] = ET[idx[r]][:]
    const float4* ET4 = (const float4*)ET;
    float4* out4 = (float4*)(out + rowbase * DIM);
    #pragma unroll
    for (int p = 0; p < 4; ++p) {
        int f = p * 256 + tid;
        int r = f >> 4, dq = f & 15;
        out4[f] = ET4[rowidx[r] * 16 + dq];
    }
}

// Emulate the numpy f32 reference chain for ambiguous rows.
__global__ void vq_refine(const float* __restrict__ x,
                          const float* __restrict__ ET,
                          const float* __restrict__ ckseq,
                          float* __restrict__ out,
                          const int* __restrict__ count,
                          const int* __restrict__ list, int list_cap) {
    #pragma clang fp contract(off)
    int gtid = blockIdx.x * blockDim.x + threadIdx.x;
    int wave = gtid >> 6;
    int lane = threadIdx.x & 63;
    int nw = (gridDim.x * blockDim.x) >> 6;
    int n = *count;
    if (n > list_cap) n = list_cap;
    for (int w = wave; w < n; w += nw) {
        int row = list[w];
        const float* z = x + row * DIM;
        float zr[DIM];
        #pragma unroll
        for (int d = 0; d < DIM; ++d) zr[d] = z[d];

        // ||z||^2: numpy pairwise_sum for n=64 (8-accumulator unrolled)
        float r8[8];
        #pragma unroll
        for (int j = 0; j < 8; ++j) r8[j] = zr[j] * zr[j];
        #pragma unroll
        for (int i = 8; i < 64; i += 8)
            #pragma unroll
            for (int j = 0; j < 8; ++j) {
                float q = zr[i + j] * zr[i + j];  // rounded square
                r8[j] = r8[j] + q;                // separate add (no fma)
            }
        float A = ((r8[0] + r8[1]) + (r8[2] + r8[3]))
                + ((r8[4] + r8[5]) + (r8[6] + r8[7]));

        float best = 1e30f;
        int bid = 0x7fffffff;
        for (int j = 0; j < 16; ++j) {
            int k = lane + 64 * j;            // ascending per lane
            const float* e = ET + k * DIM;
            float s = 0.f;                    // BLAS-style sequential FMA chain
            #pragma unroll
            for (int d = 0; d < DIM; ++d)
                s = fmaf(zr[d], e[d], s);
            float t1 = A + ckseq[k];          // fl32(A + B_k)
            float dist = t1 - 2.0f * s;       // fl32(t1 - 2*sim), no contraction
            if (dist < best) { best = dist; bid = k; }
        }
        // wave argmin reduce, first-index tie-break
        for (int off = 32; off; off >>= 1) {
            float ob = __shfl_down(best, off);
            int   oi = __shfl_down(bid, off);
            if (ob < best || (ob == best && oi < bid)) { best = ob; bid = oi; }
        }
        bid = __shfl(bid, 0);
        out[row * DIM + lane] = ET[bid * DIM + lane];
    }
}

extern "C" void kernel_launch(void* const* d_in, const int* in_sizes, int n_in,
                              void* d_out, int out_size, void* d_ws, size_t ws_size,
                              hipStream_t stream) {
    const float* x = (const float*)d_in[0];
    const float* E = (const float*)d_in[1];
    float* out = (float*)d_out;

    char* ws = (char*)d_ws;
    float* ET  = (float*)(ws + ET_OFF);
    float* ck  = (float*)(ws + CK_OFF);
    int*   cnt = (int*)(ws + CNT_OFF);
    int*   lst = (int*)(ws + LIST_OFF);
    long long avail = (long long)ws_size - LIST_OFF;
    int list_cap = avail > 0 ? (int)(avail / 4) : 0;
    if (list_cap > NROWS) list_cap = NROWS;

    hipMemsetAsync(cnt, 0, sizeof(int), stream);
    vq_prep<<<4, 256, 0, stream>>>(E, ET, ck);
    vq_main<<<NROWS / RB, 256, 0, stream>>>(x, E, ck, ET, out, cnt, lst, list_cap);
    vq_refine<<<128, 256, 0, stream>>>(x, ET, ck, out, cnt, lst, list_cap);
}